// Round 2
// baseline (251.579 us; speedup 1.0000x reference)
//
#include <hip/hip_runtime.h>
#include <stdint.h>

#define BN 16384
#define DK 1024
#define CN 100
#define CP 112      // padded col count
#define CP2 224     // hi rows [0,112) + lo rows [112,224) in wT
#define ROWS 64
#define THREADS 256
#define KS 32       // K per staged tile
#define NSTEP (DK / KS)
#define XP 40       // LDS row pitch in ushorts (32 data + 8 pad -> conflict-free)
#define GP 112      // g_buf pitch (bf16 elements)
#define MAXM 2048

typedef __attribute__((ext_vector_type(4))) float f32x4;
typedef __attribute__((ext_vector_type(8))) short bf16x8;
typedef __attribute__((ext_vector_type(4))) unsigned short u16x4;
typedef unsigned short ushort_t;
typedef unsigned int uint_t;

__device__ __forceinline__ ushort_t f2bf(float f) {
    uint_t u = __float_as_uint(f);
    uint_t r = u + 0x7FFFu + ((u >> 16) & 1u);   // RNE
    return (ushort_t)(r >> 16);
}
__device__ __forceinline__ float bf2f(ushort_t h) {
    return __uint_as_float(((uint_t)h) << 16);
}

// ---------------- init (scalars only) ----------------
__global__ void k_init(float* ce_sum, float* term_sum, int* present) {
    *ce_sum = 0.f; *term_sum = 0.f; *present = 0;
}

// ---------------- W -> transposed, padded, hi/lo split bf16 ----------------
__global__ __launch_bounds__(256) void k_prep(const float* __restrict__ W,
                                              ushort_t* __restrict__ wT) {
    const int c = blockIdx.x;          // 0..111
    for (int k = threadIdx.x; k < DK; k += 256) {
        float v = (c < CN) ? W[(size_t)k * CN + c] : 0.f;
        ushort_t hb = f2bf(v);
        float lo = v - bf2f(hb);
        wT[(size_t)c * DK + k] = hb;
        wT[(size_t)(c + CP) * DK + k] = f2bf(lo);
    }
}

// ---------------- main: x@W (MFMA, hi/lo split) + softmax + g/ce ----------------
__global__ __launch_bounds__(THREADS) void k_main(
    const float* __restrict__ x, const ushort_t* __restrict__ wT,
    const int* __restrict__ y, ushort_t* __restrict__ g_buf,
    float* __restrict__ ce_buf, float* __restrict__ ce_sum) {

    __shared__ __align__(16) ushort_t xh[2][ROWS][XP];
    __shared__ __align__(16) ushort_t xl[2][ROWS][XP];
    __shared__ __align__(16) ushort_t wl[2][CP2][XP];
    __shared__ float red[THREADS];

    const int tid = threadIdx.x;
    const int lane = tid & 63;
    const int wv = tid >> 6;        // wave 0..3 -> rows wv*16..wv*16+15
    const int l15 = lane & 15;
    const int lg = lane >> 4;       // k-group 0..3
    const int row0 = blockIdx.x * ROWS;

    // X staging: 2 float4/thread. f4 idx = tid (+256): row = idx>>3, kq=(idx&7)*4
    const int xr0 = tid >> 3;            // 0..31
    const int xkq = (tid & 7) * 4;       // 0..28
    const float* xg0 = x + (size_t)(row0 + xr0) * DK + xkq;
    const float* xg1 = x + (size_t)(row0 + xr0 + 32) * DK + xkq;

    // W staging: 7 b64 chunks/thread. chunk i = tid+256j: c=i>>3, ko=i&7
    int woff[7], wc[7], wko[7];
#pragma unroll
    for (int j = 0; j < 7; ++j) {
        int i = tid + 256 * j;
        wc[j] = i >> 3; wko[j] = i & 7;
        woff[j] = wc[j] * DK + wko[j] * 4;
    }

    f32x4 acc[7];
#pragma unroll
    for (int t = 0; t < 7; ++t) acc[t] = (f32x4){0.f, 0.f, 0.f, 0.f};

    float4 xs0 = *(const float4*)xg0;
    float4 xs1 = *(const float4*)xg1;
    u16x4 wsv[7];
#pragma unroll
    for (int j = 0; j < 7; ++j) wsv[j] = *(const u16x4*)(wT + woff[j]);

    // stage buffer 0
    {
        u16x4 h, l;
#pragma unroll
        for (int e = 0; e < 4; ++e) {
            float f = e == 0 ? xs0.x : e == 1 ? xs0.y : e == 2 ? xs0.z : xs0.w;
            ushort_t hb = f2bf(f); h[e] = hb; l[e] = f2bf(f - bf2f(hb));
        }
        *(u16x4*)&xh[0][xr0][xkq] = h; *(u16x4*)&xl[0][xr0][xkq] = l;
#pragma unroll
        for (int e = 0; e < 4; ++e) {
            float f = e == 0 ? xs1.x : e == 1 ? xs1.y : e == 2 ? xs1.z : xs1.w;
            ushort_t hb = f2bf(f); h[e] = hb; l[e] = f2bf(f - bf2f(hb));
        }
        *(u16x4*)&xh[0][xr0 + 32][xkq] = h; *(u16x4*)&xl[0][xr0 + 32][xkq] = l;
#pragma unroll
        for (int j = 0; j < 7; ++j) *(u16x4*)&wl[0][wc[j]][wko[j] * 4] = wsv[j];
    }

    const int arow = wv * 16 + l15;
    for (int st = 0; st < NSTEP; ++st) {
        const int b = st & 1;
        __syncthreads();
        if (st + 1 < NSTEP) {
            const int ks = (st + 1) * KS;
            xs0 = *(const float4*)(xg0 + ks);
            xs1 = *(const float4*)(xg1 + ks);
#pragma unroll
            for (int j = 0; j < 7; ++j) wsv[j] = *(const u16x4*)(wT + woff[j] + ks);
        }
        // compute on buffer b
        bf16x8 ah = *(const bf16x8*)&xh[b][arow][lg * 8];
        bf16x8 al = *(const bf16x8*)&xl[b][arow][lg * 8];
#pragma unroll
        for (int t = 0; t < 7; ++t) {
            const int c = t * 16 + l15;
            bf16x8 bh = *(const bf16x8*)&wl[b][c][lg * 8];
            bf16x8 bl = *(const bf16x8*)&wl[b][c + CP][lg * 8];
            acc[t] = __builtin_amdgcn_mfma_f32_16x16x32_bf16(ah, bh, acc[t], 0, 0, 0);
            acc[t] = __builtin_amdgcn_mfma_f32_16x16x32_bf16(ah, bl, acc[t], 0, 0, 0);
            acc[t] = __builtin_amdgcn_mfma_f32_16x16x32_bf16(al, bh, acc[t], 0, 0, 0);
        }
        // stage next buffer
        if (st + 1 < NSTEP) {
            const int nb = b ^ 1;
            u16x4 h, l;
#pragma unroll
            for (int e = 0; e < 4; ++e) {
                float f = e == 0 ? xs0.x : e == 1 ? xs0.y : e == 2 ? xs0.z : xs0.w;
                ushort_t hb = f2bf(f); h[e] = hb; l[e] = f2bf(f - bf2f(hb));
            }
            *(u16x4*)&xh[nb][xr0][xkq] = h; *(u16x4*)&xl[nb][xr0][xkq] = l;
#pragma unroll
            for (int e = 0; e < 4; ++e) {
                float f = e == 0 ? xs1.x : e == 1 ? xs1.y : e == 2 ? xs1.z : xs1.w;
                ushort_t hb = f2bf(f); h[e] = hb; l[e] = f2bf(f - bf2f(hb));
            }
            *(u16x4*)&xh[nb][xr0 + 32][xkq] = h; *(u16x4*)&xl[nb][xr0 + 32][xkq] = l;
#pragma unroll
            for (int j = 0; j < 7; ++j) *(u16x4*)&wl[nb][wc[j]][wko[j] * 4] = wsv[j];
        }
    }

    // epilogue: softmax per row. lane's rows: wv*16 + lg*4 + rr ; cols l15+16t
    float ce_acc = 0.f;
#pragma unroll
    for (int rr = 0; rr < 4; ++rr) {
        const int grow = row0 + wv * 16 + lg * 4 + rr;
        const int yr = y[grow];
        float m = -3.4e38f;
#pragma unroll
        for (int t = 0; t < 7; ++t) {
            int c = l15 + 16 * t;
            if (c < CN) m = fmaxf(m, acc[t][rr]);
        }
#pragma unroll
        for (int s = 1; s < 16; s <<= 1) m = fmaxf(m, __shfl_xor(m, s));
        float ev[7], ssum = 0.f;
#pragma unroll
        for (int t = 0; t < 7; ++t) {
            int c = l15 + 16 * t;
            ev[t] = (c < CN) ? __expf(acc[t][rr] - m) : 0.f;
            ssum += ev[t];
        }
#pragma unroll
        for (int s = 1; s < 16; s <<= 1) ssum += __shfl_xor(ssum, s);
        const float lse = m + __logf(ssum);
        const float inv = 1.f / ssum;
#pragma unroll
        for (int t = 0; t < 7; ++t) {
            int c = l15 + 16 * t;
            float g = (c < CN) ? (ev[t] * inv - ((c == yr) ? 1.f : 0.f)) : 0.f;
            g_buf[(size_t)grow * GP + c] = f2bf(g);
            if (c == yr) {
                float ce = lse - acc[t][rr];
                ce_buf[grow] = ce;
                ce_acc += ce;
            }
        }
    }
    red[tid] = ce_acc;
    __syncthreads();
    for (int s = 128; s > 0; s >>= 1) {
        if (tid < s) red[tid] += red[tid + s];
        __syncthreads();
    }
    if (tid == 0) atomicAdd(ce_sum, red[0]);
}

// ---------------- per-class gather: counts, anchor(argmin ce), class sums ----------------
__global__ __launch_bounds__(128) void k_classsum(
    const int* __restrict__ y, const ushort_t* __restrict__ g_buf,
    const float* __restrict__ ce_buf, float* __restrict__ class_sum,
    int* __restrict__ counts, int* __restrict__ anchor) {
    __shared__ int mem[MAXM];
    __shared__ int mcnt;
    __shared__ unsigned long long pmin[2];
    const int c = blockIdx.x, tid = threadIdx.x;
    if (tid == 0) mcnt = 0;
    __syncthreads();
    for (int i = tid; i < BN; i += 128)
        if (y[i] == c) { int p = atomicAdd(&mcnt, 1); if (p < MAXM) mem[p] = i; }
    __syncthreads();
    const int cnt = mcnt < MAXM ? mcnt : MAXM;
    if (tid == 0) { counts[c] = cnt; if (cnt == 0) anchor[c] = 0; }
    if (cnt == 0) return;
    // anchor = argmin ce (ties -> lowest idx)
    unsigned long long pk = ~0ULL;
    for (int p = tid; p < cnt; p += 128) {
        int i = mem[p];
        float ce = fmaxf(ce_buf[i], 0.f);
        unsigned long long v =
            ((unsigned long long)__float_as_uint(ce) << 32) | (unsigned int)i;
        if (v < pk) pk = v;
    }
#pragma unroll
    for (int s = 1; s < 64; s <<= 1) {
        unsigned long long o = __shfl_xor(pk, s);
        if (o < pk) pk = o;
    }
    if ((tid & 63) == 0) pmin[tid >> 6] = pk;
    __syncthreads();
    if (tid == 0) {
        unsigned long long v = pmin[0] < pmin[1] ? pmin[0] : pmin[1];
        anchor[c] = (int)(v & 0xffffffffULL);
    }
    // class sums over members (coalesced 224B rows)
    if (tid < CP) {
        float s = 0.f;
        for (int p = 0; p < cnt; ++p)
            s += bf2f(g_buf[(size_t)mem[p] * GP + tid]);
        class_sum[c * CP + tid] = s;
    }
}

// ---------------- per-class cosines via u = W*v (no Gram matrix) ----------------
__global__ __launch_bounds__(128) void k_class(
    const float* __restrict__ W, const ushort_t* __restrict__ g_buf,
    const float* __restrict__ class_sum, const int* __restrict__ counts,
    const int* __restrict__ anchor, float* __restrict__ term_sum,
    int* __restrict__ present) {
    __shared__ float a_s[CN], p_s[CN], n_s[CN];
    __shared__ float wsum[2][5];
    const int c = blockIdx.x, t = threadIdx.x;
    const int cnt = counts[c];
    if (cnt == 0) return;
    if (t < CN) {
        float a = bf2f(g_buf[(size_t)anchor[c] * GP + t]);
        float cs = class_sum[c * CP + t];
        float tot = 0.f;
#pragma unroll 4
        for (int k = 0; k < CN; ++k) tot += class_sum[k * CP + t];
        a_s[t] = a;
        p_s[t] = cs - a;
        n_s[t] = tot - cs;
    }
    __syncthreads();
    float aa = 0, ap = 0, pp = 0, an = 0, nn = 0;
    for (int k = t; k < DK; k += 128) {
        const float* wr = W + (size_t)k * CN;
        float ua = 0, up = 0, un = 0;
#pragma unroll 4
        for (int j = 0; j < CN; ++j) {
            float wv = wr[j];
            ua = fmaf(wv, a_s[j], ua);
            up = fmaf(wv, p_s[j], up);
            un = fmaf(wv, n_s[j], un);
        }
        aa = fmaf(ua, ua, aa); ap = fmaf(ua, up, ap); pp = fmaf(up, up, pp);
        an = fmaf(ua, un, an); nn = fmaf(un, un, nn);
    }
#pragma unroll
    for (int s = 1; s < 64; s <<= 1) {
        aa += __shfl_xor(aa, s); ap += __shfl_xor(ap, s); pp += __shfl_xor(pp, s);
        an += __shfl_xor(an, s); nn += __shfl_xor(nn, s);
    }
    const int wid = t >> 6;
    if ((t & 63) == 0) {
        wsum[wid][0] = aa; wsum[wid][1] = ap; wsum[wid][2] = pp;
        wsum[wid][3] = an; wsum[wid][4] = nn;
    }
    __syncthreads();
    if (t == 0) {
        aa = wsum[0][0] + wsum[1][0];
        ap = wsum[0][1] + wsum[1][1];
        pp = wsum[0][2] + wsum[1][2];
        an = wsum[0][3] + wsum[1][3];
        nn = wsum[0][4] + wsum[1][4];
        float na  = sqrtf(fmaxf(aa, 0.f));
        float np_ = sqrtf(fmaxf(pp, 0.f));
        float nn_ = sqrtf(fmaxf(nn, 0.f));
        float cos_ap = ap / (fmaxf(na, 1e-12f) * fmaxf(np_, 1e-12f));
        float cos_an = an / (fmaxf(na, 1e-12f) * fmaxf(nn_, 1e-12f));
        atomicAdd(term_sum, cos_ap - cos_an);
        atomicAdd(present, 1);
    }
}

// ---------------- final scalar ----------------
__global__ void k_final(const float* ce_sum, const float* term_sum,
                        const int* present, float* out) {
    float npres = fmaxf((float)(*present), 1.f);
    out[0] = (*ce_sum) * (1.f / (float)BN) - 2.0f * ((*term_sum) / npres);
}

extern "C" void kernel_launch(void* const* d_in, const int* in_sizes, int n_in,
                              void* d_out, int out_size, void* d_ws, size_t ws_size,
                              hipStream_t stream) {
    const float* x = (const float*)d_in[0];
    const float* W = (const float*)d_in[1];
    const int* y = (const int*)d_in[2];

    char* ws = (char*)d_ws;
    ushort_t* wT      = (ushort_t*)(ws);                    // 224*1024*2 = 458752
    ushort_t* g_buf   = (ushort_t*)(ws + 458752);           // 16384*112*2 = 3670016
    float*    ce_buf  = (float*)(ws + 4128768);             // 16384*4 = 65536
    float*    cls     = (float*)(ws + 4194304);             // 100*112*4 = 44800
    int*      counts  = (int*)(ws + 4239104);               // 400
    int*      anchor  = (int*)(ws + 4239504);               // 400
    float*    ce_sum  = (float*)(ws + 4239904);
    float*    term_sum= (float*)(ws + 4239908);
    int*      present = (int*)(ws + 4239912);

    k_init<<<1, 1, 0, stream>>>(ce_sum, term_sum, present);
    k_prep<<<CP, 256, 0, stream>>>(W, wT);
    k_main<<<BN / ROWS, THREADS, 0, stream>>>(x, wT, y, g_buf, ce_buf, ce_sum);
    k_classsum<<<CN, 128, 0, stream>>>(y, g_buf, ce_buf, cls, counts, anchor);
    k_class<<<CN, 128, 0, stream>>>(W, g_buf, cls, counts, anchor, term_sum, present);
    k_final<<<1, 1, 0, stream>>>(ce_sum, term_sum, present, (float*)d_out);
}

// Round 3
// 221.079 us; speedup vs baseline: 1.1380x; 1.1380x over previous
//
#include <hip/hip_runtime.h>
#include <stdint.h>

#define BN 16384
#define DK 1024
#define CN 100
#define CP 112      // padded col count
#define CP2 224     // hi rows [0,112) + lo rows [112,224) in wT
#define ROWS 64
#define THREADS 256
#define KS 32       // K per staged tile
#define NSTEP (DK / KS)
#define XP 40       // LDS row pitch in ushorts (32 data + 8 pad -> conflict-free)
#define GP 112      // g_buf pitch (bf16 elements)
#define PSB 64      // psum blocks
#define PSROWS (BN / PSB)   // 256 rows per psum block

typedef __attribute__((ext_vector_type(4))) float f32x4;
typedef __attribute__((ext_vector_type(8))) short bf16x8;
typedef __attribute__((ext_vector_type(4))) unsigned short u16x4;
typedef unsigned short ushort_t;
typedef unsigned int uint_t;

__device__ __forceinline__ ushort_t f2bf(float f) {
    uint_t u = __float_as_uint(f);
    uint_t r = u + 0x7FFFu + ((u >> 16) & 1u);   // RNE
    return (ushort_t)(r >> 16);
}
__device__ __forceinline__ float bf2f(ushort_t h) {
    return __uint_as_float(((uint_t)h) << 16);
}

// ---------------- prep: W -> wT (transposed, padded, hi/lo bf16) + inits ----------------
__global__ __launch_bounds__(256) void k_prep(const float* __restrict__ W,
        ushort_t* __restrict__ wT, unsigned long long* __restrict__ packed,
        int* __restrict__ counts, float* ce_sum, float* term_sum, int* present) {
    __shared__ float tile[32][CN];
    const int tid = threadIdx.x;
    const int k0 = blockIdx.x * 32;
    for (int i = tid; i < 32 * CN; i += 256) {
        int k = i / CN, c = i - k * CN;
        tile[k][c] = W[(size_t)(k0 + k) * CN + c];   // coalesced (c contiguous)
    }
    __syncthreads();
    for (int i = tid; i < CP * 8; i += 256) {
        int c = i >> 3, kq = (i & 7) * 4;
        u16x4 h, l;
#pragma unroll
        for (int e = 0; e < 4; ++e) {
            float v = (c < CN) ? tile[kq + e][c] : 0.f;
            ushort_t hb = f2bf(v);
            h[e] = hb; l[e] = f2bf(v - bf2f(hb));
        }
        *(u16x4*)&wT[(size_t)c * DK + k0 + kq] = h;
        *(u16x4*)&wT[(size_t)(c + CP) * DK + k0 + kq] = l;
    }
    if (blockIdx.x == 0) {
        if (tid < CN) { packed[tid] = ~0ULL; counts[tid] = 0; }
        if (tid == 0) { *ce_sum = 0.f; *term_sum = 0.f; *present = 0; }
    }
}

// ---------------- main: x@W (MFMA, hi/lo split) + softmax + g + ce + anchor ----------------
__global__ __launch_bounds__(THREADS) void k_main(
    const float* __restrict__ x, const ushort_t* __restrict__ wT,
    const int* __restrict__ y, ushort_t* __restrict__ g_buf,
    unsigned long long* __restrict__ packed, int* __restrict__ counts,
    float* __restrict__ ce_sum) {

    __shared__ __align__(16) ushort_t xh[2][ROWS][XP];
    __shared__ __align__(16) ushort_t xl[2][ROWS][XP];
    __shared__ __align__(16) ushort_t wl[2][CP2][XP];
    __shared__ float red[THREADS];

    const int tid = threadIdx.x;
    const int lane = tid & 63;
    const int wv = tid >> 6;        // wave 0..3 -> rows wv*16..wv*16+15
    const int l15 = lane & 15;
    const int lg = lane >> 4;       // k-group 0..3
    const int row0 = blockIdx.x * ROWS;

    // X staging: 2 float4/thread
    const int xr0 = tid >> 3;            // 0..31
    const int xkq = (tid & 7) * 4;       // 0..28
    const float* xg0 = x + (size_t)(row0 + xr0) * DK + xkq;
    const float* xg1 = x + (size_t)(row0 + xr0 + 32) * DK + xkq;

    // W staging: 7 b64 chunks/thread
    int woff[7], wc[7], wko[7];
#pragma unroll
    for (int j = 0; j < 7; ++j) {
        int i = tid + 256 * j;
        wc[j] = i >> 3; wko[j] = i & 7;
        woff[j] = wc[j] * DK + wko[j] * 4;
    }

    f32x4 acc[7];
#pragma unroll
    for (int t = 0; t < 7; ++t) acc[t] = (f32x4){0.f, 0.f, 0.f, 0.f};

    float4 xs0 = *(const float4*)xg0;
    float4 xs1 = *(const float4*)xg1;
    u16x4 wsv[7];
#pragma unroll
    for (int j = 0; j < 7; ++j) wsv[j] = *(const u16x4*)(wT + woff[j]);

    // stage buffer 0
    {
        u16x4 h, l;
#pragma unroll
        for (int e = 0; e < 4; ++e) {
            float f = e == 0 ? xs0.x : e == 1 ? xs0.y : e == 2 ? xs0.z : xs0.w;
            ushort_t hb = f2bf(f); h[e] = hb; l[e] = f2bf(f - bf2f(hb));
        }
        *(u16x4*)&xh[0][xr0][xkq] = h; *(u16x4*)&xl[0][xr0][xkq] = l;
#pragma unroll
        for (int e = 0; e < 4; ++e) {
            float f = e == 0 ? xs1.x : e == 1 ? xs1.y : e == 2 ? xs1.z : xs1.w;
            ushort_t hb = f2bf(f); h[e] = hb; l[e] = f2bf(f - bf2f(hb));
        }
        *(u16x4*)&xh[0][xr0 + 32][xkq] = h; *(u16x4*)&xl[0][xr0 + 32][xkq] = l;
#pragma unroll
        for (int j = 0; j < 7; ++j) *(u16x4*)&wl[0][wc[j]][wko[j] * 4] = wsv[j];
    }

    const int arow = wv * 16 + l15;
    for (int st = 0; st < NSTEP; ++st) {
        const int b = st & 1;
        __syncthreads();
        if (st + 1 < NSTEP) {
            const int ks = (st + 1) * KS;
            xs0 = *(const float4*)(xg0 + ks);
            xs1 = *(const float4*)(xg1 + ks);
#pragma unroll
            for (int j = 0; j < 7; ++j) wsv[j] = *(const u16x4*)(wT + woff[j] + ks);
        }
        // compute on buffer b
        bf16x8 ah = *(const bf16x8*)&xh[b][arow][lg * 8];
        bf16x8 al = *(const bf16x8*)&xl[b][arow][lg * 8];
#pragma unroll
        for (int t = 0; t < 7; ++t) {
            const int c = t * 16 + l15;
            bf16x8 bh = *(const bf16x8*)&wl[b][c][lg * 8];
            bf16x8 bl = *(const bf16x8*)&wl[b][c + CP][lg * 8];
            acc[t] = __builtin_amdgcn_mfma_f32_16x16x32_bf16(ah, bh, acc[t], 0, 0, 0);
            acc[t] = __builtin_amdgcn_mfma_f32_16x16x32_bf16(ah, bl, acc[t], 0, 0, 0);
            acc[t] = __builtin_amdgcn_mfma_f32_16x16x32_bf16(al, bh, acc[t], 0, 0, 0);
        }
        // stage next buffer
        if (st + 1 < NSTEP) {
            const int nb = b ^ 1;
            u16x4 h, l;
#pragma unroll
            for (int e = 0; e < 4; ++e) {
                float f = e == 0 ? xs0.x : e == 1 ? xs0.y : e == 2 ? xs0.z : xs0.w;
                ushort_t hb = f2bf(f); h[e] = hb; l[e] = f2bf(f - bf2f(hb));
            }
            *(u16x4*)&xh[nb][xr0][xkq] = h; *(u16x4*)&xl[nb][xr0][xkq] = l;
#pragma unroll
            for (int e = 0; e < 4; ++e) {
                float f = e == 0 ? xs1.x : e == 1 ? xs1.y : e == 2 ? xs1.z : xs1.w;
                ushort_t hb = f2bf(f); h[e] = hb; l[e] = f2bf(f - bf2f(hb));
            }
            *(u16x4*)&xh[nb][xr0 + 32][xkq] = h; *(u16x4*)&xl[nb][xr0 + 32][xkq] = l;
#pragma unroll
            for (int j = 0; j < 7; ++j) *(u16x4*)&wl[nb][wc[j]][wko[j] * 4] = wsv[j];
        }
    }

    // epilogue: softmax per row. lane's rows: wv*16 + lg*4 + rr ; cols l15+16t
    float ce_acc = 0.f;
#pragma unroll
    for (int rr = 0; rr < 4; ++rr) {
        const int grow = row0 + wv * 16 + lg * 4 + rr;
        const int yr = y[grow];
        float m = -3.4e38f;
#pragma unroll
        for (int t = 0; t < 7; ++t) {
            int c = l15 + 16 * t;
            if (c < CN) m = fmaxf(m, acc[t][rr]);
        }
#pragma unroll
        for (int s = 1; s < 16; s <<= 1) m = fmaxf(m, __shfl_xor(m, s));
        float ev[7], ssum = 0.f;
#pragma unroll
        for (int t = 0; t < 7; ++t) {
            int c = l15 + 16 * t;
            ev[t] = (c < CN) ? __expf(acc[t][rr] - m) : 0.f;
            ssum += ev[t];
        }
#pragma unroll
        for (int s = 1; s < 16; s <<= 1) ssum += __shfl_xor(ssum, s);
        const float lse = m + __logf(ssum);
        const float inv = 1.f / ssum;
#pragma unroll
        for (int t = 0; t < 7; ++t) {
            int c = l15 + 16 * t;
            float g = (c < CN) ? (ev[t] * inv - ((c == yr) ? 1.f : 0.f)) : 0.f;
            g_buf[(size_t)grow * GP + c] = f2bf(g);
            if (c == yr) {
                float ce = lse - acc[t][rr];
                ce_acc += ce;
                unsigned long long pk =
                    ((unsigned long long)__float_as_uint(fmaxf(ce, 0.f)) << 32) |
                    (unsigned int)grow;
                atomicMin(&packed[yr], pk);   // argmin ce; ties -> lowest row idx
                atomicAdd(&counts[yr], 1);
            }
        }
    }
    red[tid] = ce_acc;
    __syncthreads();
    for (int s = 128; s > 0; s >>= 1) {
        if (tid < s) red[tid] += red[tid + s];
        __syncthreads();
    }
    if (tid == 0) atomicAdd(ce_sum, red[0]);
}

// ---------------- Gram: M = W^T W (112x112 fp32) from wT via MFMA ----------------
__global__ __launch_bounds__(64) void k_gram(const ushort_t* __restrict__ wT,
                                             float* __restrict__ M) {
    const int lane = threadIdx.x;
    const int c1t = blockIdx.x / 7, c2t = blockIdx.x % 7;
    const int l15 = lane & 15, lg = lane >> 4;
    const ushort_t* pa = wT + (size_t)(c1t * 16 + l15) * DK + lg * 8;
    const ushort_t* pb = wT + (size_t)(c2t * 16 + l15) * DK + lg * 8;
    f32x4 acc = (f32x4){0.f, 0.f, 0.f, 0.f};
#pragma unroll 4
    for (int st = 0; st < NSTEP; ++st) {
        bf16x8 ah = *(const bf16x8*)(pa + st * KS);
        bf16x8 al = *(const bf16x8*)(pa + (size_t)CP * DK + st * KS);
        bf16x8 bh = *(const bf16x8*)(pb + st * KS);
        bf16x8 bl = *(const bf16x8*)(pb + (size_t)CP * DK + st * KS);
        acc = __builtin_amdgcn_mfma_f32_16x16x32_bf16(ah, bh, acc, 0, 0, 0);
        acc = __builtin_amdgcn_mfma_f32_16x16x32_bf16(ah, bl, acc, 0, 0, 0);
        acc = __builtin_amdgcn_mfma_f32_16x16x32_bf16(al, bh, acc, 0, 0, 0);
    }
#pragma unroll
    for (int r = 0; r < 4; ++r) {
        int row = lg * 4 + r, col = l15;
        M[(size_t)(c1t * 16 + row) * CP + c2t * 16 + col] = acc[r];
    }
}

// ---------------- partial class sums (segment reduction, stage 1) ----------------
__global__ __launch_bounds__(256) void k_psum(const int* __restrict__ y,
        const ushort_t* __restrict__ g_buf, float* __restrict__ partial) {
    __shared__ float acc[2][CN][CP];   // 89.6 KB (gfx950 allows up to 160 KB)
    const int tid = threadIdx.x;
    const int team = tid >> 7, j = tid & 127;
    float* af = (float*)acc;
    for (int i = tid; i < 2 * CN * CP; i += 256) af[i] = 0.f;
    __syncthreads();
    const int row0 = blockIdx.x * PSROWS;
    for (int it = 0; it < PSROWS / 2; ++it) {
        const int row = row0 + it * 2 + team;
        const int cls = y[row];
        if (j < CP) acc[team][cls][j] += bf2f(g_buf[(size_t)row * GP + j]);
    }
    __syncthreads();
    float* out = partial + (size_t)blockIdx.x * (CN * CP);
    for (int i = tid; i < CN * CP; i += 256) out[i] = af[i] + af[i + CN * CP];
}

// ---------------- reduce partials -> class_sum ----------------
__global__ __launch_bounds__(256) void k_reduce(const float* __restrict__ partial,
                                                float* __restrict__ cls) {
    const int i = blockIdx.x * 256 + threadIdx.x;
    if (i >= CN * CP) return;
    float s = 0.f;
#pragma unroll 4
    for (int b = 0; b < PSB; ++b) s += partial[(size_t)b * (CN * CP) + i];
    cls[i] = s;
}

// ---------------- per-class cosines via symmetric Gram matrix ----------------
__global__ __launch_bounds__(128) void k_class(
    const float* __restrict__ M, const ushort_t* __restrict__ g_buf,
    const float* __restrict__ cls, const int* __restrict__ counts,
    const unsigned long long* __restrict__ packed,
    float* __restrict__ term_sum, int* __restrict__ present) {
    __shared__ float a_s[CP], p_s[CP], n_s[CP];
    __shared__ float wsum[2][5];
    const int c = blockIdx.x, t = threadIdx.x;
    if (counts[c] == 0) return;
    const int anchor = (int)(packed[c] & 0xffffffffULL);
    if (t < CP) {
        float a = bf2f(g_buf[(size_t)anchor * GP + t]);
        float cs = cls[c * CP + t];
        float tot = 0.f;
#pragma unroll 4
        for (int k = 0; k < CN; ++k) tot += cls[k * CP + t];   // coalesced
        a_s[t] = a; p_s[t] = cs - a; n_s[t] = tot - cs;
    }
    __syncthreads();
    float aa = 0, ap = 0, pp = 0, an = 0, nn = 0;
    if (t < CP) {
        float ua = 0, up = 0, un = 0;
#pragma unroll 4
        for (int k = 0; k < CP; ++k) {
            float m = M[(size_t)k * CP + t];   // M symmetric -> coalesced rows
            ua = fmaf(m, a_s[k], ua);
            up = fmaf(m, p_s[k], up);
            un = fmaf(m, n_s[k], un);
        }
        aa = a_s[t] * ua; ap = a_s[t] * up; pp = p_s[t] * up;
        an = a_s[t] * un; nn = n_s[t] * un;
    }
#pragma unroll
    for (int s = 1; s < 64; s <<= 1) {
        aa += __shfl_xor(aa, s); ap += __shfl_xor(ap, s); pp += __shfl_xor(pp, s);
        an += __shfl_xor(an, s); nn += __shfl_xor(nn, s);
    }
    const int wid = t >> 6;
    if ((t & 63) == 0) {
        wsum[wid][0] = aa; wsum[wid][1] = ap; wsum[wid][2] = pp;
        wsum[wid][3] = an; wsum[wid][4] = nn;
    }
    __syncthreads();
    if (t == 0) {
        aa = wsum[0][0] + wsum[1][0];
        ap = wsum[0][1] + wsum[1][1];
        pp = wsum[0][2] + wsum[1][2];
        an = wsum[0][3] + wsum[1][3];
        nn = wsum[0][4] + wsum[1][4];
        float na  = sqrtf(fmaxf(aa, 0.f));
        float np_ = sqrtf(fmaxf(pp, 0.f));
        float nn_ = sqrtf(fmaxf(nn, 0.f));
        float cos_ap = ap / (fmaxf(na, 1e-12f) * fmaxf(np_, 1e-12f));
        float cos_an = an / (fmaxf(na, 1e-12f) * fmaxf(nn_, 1e-12f));
        atomicAdd(term_sum, cos_ap - cos_an);
        atomicAdd(present, 1);
    }
}

// ---------------- final scalar ----------------
__global__ void k_final(const float* ce_sum, const float* term_sum,
                        const int* present, float* out) {
    float npres = fmaxf((float)(*present), 1.f);
    out[0] = (*ce_sum) * (1.f / (float)BN) - 2.0f * ((*term_sum) / npres);
}

extern "C" void kernel_launch(void* const* d_in, const int* in_sizes, int n_in,
                              void* d_out, int out_size, void* d_ws, size_t ws_size,
                              hipStream_t stream) {
    const float* x = (const float*)d_in[0];
    const float* W = (const float*)d_in[1];
    const int* y = (const int*)d_in[2];

    char* ws = (char*)d_ws;
    ushort_t* wT      = (ushort_t*)(ws);                    // 458752 B
    ushort_t* g_buf   = (ushort_t*)(ws + 458752);           // 3670016 B
    float*    partial = (float*)(ws + 4128768);             // 64*11200*4 = 2867200 B
    float*    cls     = (float*)(ws + 6995968);             // 44800 B
    float*    M       = (float*)(ws + 7040768);             // 50176 B
    unsigned long long* packed = (unsigned long long*)(ws + 7090944);  // 800 B
    int*      counts  = (int*)(ws + 7091744);               // 400 B
    float*    ce_sum  = (float*)(ws + 7092144);
    float*    term_sum= (float*)(ws + 7092148);
    int*      present = (int*)(ws + 7092152);

    k_prep<<<DK / 32, 256, 0, stream>>>(W, wT, packed, counts, ce_sum, term_sum, present);
    k_main<<<BN / ROWS, THREADS, 0, stream>>>(x, wT, y, g_buf, packed, counts, ce_sum);
    k_gram<<<49, 64, 0, stream>>>(wT, M);
    k_psum<<<PSB, 256, 0, stream>>>(y, g_buf, partial);
    k_reduce<<<(CN * CP + 255) / 256, 256, 0, stream>>>(partial, cls);
    k_class<<<CN, 128, 0, stream>>>(M, g_buf, cls, counts, packed, term_sum, present);
    k_final<<<1, 1, 0, stream>>>(ce_sum, term_sum, present, (float*)d_out);
}